// Round 9
// baseline (408.072 us; speedup 1.0000x reference)
//
#include <hip/hip_runtime.h>
#include <hip/hip_bf16.h>
#include <stdint.h>

// R17: R16 +
//  (1) attn: XCD-affinity block remap (512%8==0, bijective): XCD j&7 owns
//      4 (b,h) groups x 16 qb (qb alternating heavy/light). The 16 blocks
//      sharing one (b,h)'s K/V (2MB) co-locate -> K/V L2-resident -> the
//      per-tile vmcnt stall on K/V prefetch (HBM ~900cy > tile compute)
//      becomes L2 ~200cy and fully hides. Theory from FETCH 113MB vs 64 ideal.
//  (2) proj gemm_bf: same XCD remap (A-panels 2MB/XCD L2-resident).
//  (3) all three converts fused into ONE pre-GEMM launch when ws_size >=
//      96MB (Wproj_bf gets own region); runtime fallback to R16 layout.
// gemm8 unchanged from R16 (its swizzle kept: 145->133 measured).

typedef __bf16 bf16x8 __attribute__((ext_vector_type(8)));
typedef float f32x4 __attribute__((ext_vector_type(4)));
typedef unsigned short u16x8 __attribute__((ext_vector_type(8)));
typedef unsigned short u16x4 __attribute__((ext_vector_type(4)));

__device__ __forceinline__ unsigned short f2bf(float f) {
  unsigned int u = __builtin_bit_cast(unsigned int, f);
  u += 0x7fff + ((u >> 16) & 1);   // RNE; values are finite
  return (unsigned short)(u >> 16);
}
__device__ __forceinline__ float bf2f(unsigned short u) {
  return __builtin_bit_cast(float, (unsigned int)u << 16);
}

__device__ __forceinline__ u16x8 cvt8(const float* p) {
  f32x4 lo = *(const f32x4*)p;
  f32x4 hi = *(const f32x4*)(p + 4);
  u16x8 r;
#pragma unroll
  for (int j = 0; j < 4; j++) { r[j] = f2bf(lo[j]); r[4 + j] = f2bf(hi[j]); }
  return r;
}

// async 16B global->LDS copy. LDS dest is wave-uniform base; HW adds lane*16.
__device__ __forceinline__ void gload16(const void* g, void* l) {
  __builtin_amdgcn_global_load_lds(
      (const __attribute__((address_space(1))) void*)g,
      (__attribute__((address_space(3))) void*)l, 16, 0, 0);
}

// ---------------------------------------------------------------------------
// fp32 -> bf16 bulk converts. Memory-bound.
// ---------------------------------------------------------------------------
__global__ __launch_bounds__(256) void f32_to_bf16(
    const float* __restrict__ src, unsigned short* __restrict__ dst, int n8) {
  int i = blockIdx.x * 256 + threadIdx.x;
  const int stride = gridDim.x * 256;
  for (; i < n8; i += stride) {
    u16x8 v = cvt8(src + (size_t)i * 8);
    *(u16x8*)&dst[(size_t)i * 8] = v;
  }
}

// two-array fused variant (x and Wqkv)
__global__ __launch_bounds__(256) void f32_to_bf16_2(
    const float* __restrict__ s0, unsigned short* __restrict__ d0, int n80,
    const float* __restrict__ s1, unsigned short* __restrict__ d1, int n81) {
  int i = blockIdx.x * 256 + threadIdx.x;
  const int stride = gridDim.x * 256;
  const int tot = n80 + n81;
  for (; i < tot; i += stride) {
    if (i < n80) {
      u16x8 v = cvt8(s0 + (size_t)i * 8);
      *(u16x8*)&d0[(size_t)i * 8] = v;
    } else {
      const int j = i - n80;
      u16x8 v = cvt8(s1 + (size_t)j * 8);
      *(u16x8*)&d1[(size_t)j * 8] = v;
    }
  }
}

// three-array fused variant (x, Wqkv, Wproj — used when ws has room)
__global__ __launch_bounds__(256) void f32_to_bf16_3(
    const float* __restrict__ s0, unsigned short* __restrict__ d0, int n80,
    const float* __restrict__ s1, unsigned short* __restrict__ d1, int n81,
    const float* __restrict__ s2, unsigned short* __restrict__ d2, int n82) {
  int i = blockIdx.x * 256 + threadIdx.x;
  const int stride = gridDim.x * 256;
  const int tot = n80 + n81 + n82;
  for (; i < tot; i += stride) {
    if (i < n80) {
      u16x8 v = cvt8(s0 + (size_t)i * 8);
      *(u16x8*)&d0[(size_t)i * 8] = v;
    } else if (i < n80 + n81) {
      const int j = i - n80;
      u16x8 v = cvt8(s1 + (size_t)j * 8);
      *(u16x8*)&d1[(size_t)j * 8] = v;
    } else {
      const int j = i - n80 - n81;
      u16x8 v = cvt8(s2 + (size_t)j * 8);
      *(u16x8*)&d2[(size_t)j * 8] = v;
    }
  }
}

// ---------------------------------------------------------------------------
// 128x128 GEMM (R10-proven): C[M][N] = A[M][K] @ B[N][K]^T, bf16 in.
// SWZ: XCD-affinity remap of the tile id (requires nwg % 8 == 0).
// ---------------------------------------------------------------------------
template <bool COF32, bool SWZ>
__global__ __launch_bounds__(256) void gemm_bf(
    const unsigned short* __restrict__ A, const unsigned short* __restrict__ B,
    void* __restrict__ Cv, int M, int N, int K) {
  __shared__ __align__(16) unsigned short Alds[128 * 32];
  __shared__ __align__(16) unsigned short Blds[128 * 32];

  const int tid  = threadIdx.x;
  const int lane = tid & 63;
  const int w    = tid >> 6;
  const int ln   = lane & 15;
  const int kq   = lane >> 4;

  int bx = blockIdx.x, by = blockIdx.y;
  if (SWZ) {
    const int nwg = gridDim.x * gridDim.y;
    const int j = by * gridDim.x + bx;
    const int s = (j & 7) * (nwg >> 3) + (j >> 3);
    bx = s % gridDim.x;
    by = s / gridDim.x;
  }
  const int m0 = by * 128;
  const int n0 = bx * 128;
  const int m_base = (w >> 1) * 64;
  const int n_base = (w & 1) * 64;

  f32x4 acc[4][4];
#pragma unroll
  for (int i = 0; i < 4; i++)
#pragma unroll
    for (int j = 0; j < 4; j++) acc[i][j] = {0.f, 0.f, 0.f, 0.f};

  const int c0 = tid;
  const int c1 = tid + 256;
  const unsigned short* Ag0 = A + (size_t)(m0 + (c0 >> 2)) * K + (c0 & 3) * 8;
  const unsigned short* Ag1 = A + (size_t)(m0 + (c1 >> 2)) * K + (c1 & 3) * 8;
  const unsigned short* Bg0 = B + (size_t)(n0 + (c0 >> 2)) * K + (c0 & 3) * 8;
  const unsigned short* Bg1 = B + (size_t)(n0 + (c1 >> 2)) * K + (c1 & 3) * 8;
  unsigned short* lA0 = &Alds[(size_t)w * 512];
  unsigned short* lA1 = &Alds[2048 + (size_t)w * 512];
  unsigned short* lB0 = &Blds[(size_t)w * 512];
  unsigned short* lB1 = &Blds[2048 + (size_t)w * 512];

  const int nk = K >> 5;
  for (int kt = 0; kt < nk; kt++) {
    const int ko = kt * 32;
    gload16(Ag0 + ko, lA0);
    gload16(Ag1 + ko, lA1);
    gload16(Bg0 + ko, lB0);
    gload16(Bg1 + ko, lB1);
    __syncthreads();

    bf16x8 af[4], bfr[4];
#pragma unroll
    for (int i = 0; i < 4; i++)
      af[i] = *(const bf16x8*)&Alds[(m_base + i * 16 + ln) * 32 + kq * 8];
#pragma unroll
    for (int j = 0; j < 4; j++)
      bfr[j] = *(const bf16x8*)&Blds[(n_base + j * 16 + ln) * 32 + kq * 8];
#pragma unroll
    for (int i = 0; i < 4; i++)
#pragma unroll
      for (int j = 0; j < 4; j++)
        acc[i][j] = __builtin_amdgcn_mfma_f32_16x16x32_bf16(af[i], bfr[j], acc[i][j], 0, 0, 0);
    __syncthreads();
  }

#pragma unroll
  for (int i = 0; i < 4; i++) {
    const int row_base = m0 + m_base + i * 16 + kq * 4;
#pragma unroll
    for (int j = 0; j < 4; j++) {
      const int col = n0 + n_base + j * 16 + ln;
#pragma unroll
      for (int r = 0; r < 4; r++) {
        const size_t idx = (size_t)(row_base + r) * N + col;
        if (COF32) ((float*)Cv)[idx] = acc[i][j][r];
        else       ((unsigned short*)Cv)[idx] = f2bf(acc[i][j][r]);
      }
    }
  }
}

// ---------------------------------------------------------------------------
// 8-phase GEMM (R12/R13/R16): 256x256, BK=64, 512 thr; ks-half-major LDS
// XOR swizzle; vmcnt(4) boundary; setprio; lgkmcnt hints; XCD tile swizzle.
// ---------------------------------------------------------------------------
template <bool COF32>
__global__ __launch_bounds__(512, 2) void gemm8(
    const unsigned short* __restrict__ A, const unsigned short* __restrict__ B,
    void* __restrict__ Cv, int M, int N, int K) {
  __shared__ __align__(1024) unsigned short As[2][16384];
  __shared__ __align__(1024) unsigned short Bs[2][16384];

  const int tid  = threadIdx.x;
  const int lane = tid & 63;
  const int w    = tid >> 6;
  const int ln   = lane & 15;
  const int kq   = lane >> 4;
  const int wm   = w >> 2;
  const int wn   = w & 3;

  const int nx  = gridDim.x;
  const int nwg = gridDim.x * gridDim.y;
  const int lin = blockIdx.y * nx + blockIdx.x;
  const int swz = (lin & 7) * (nwg >> 3) + (lin >> 3);
  const int m0 = (swz / nx) * 256;
  const int n0 = (swz % nx) * 256;

  const int kswz = (kq * 8) ^ ((ln & 8) << 1);

  const int lx = lane ^ (((lane >> 5) & 1) << 1);
  const int srow = w * 16 + (lx >> 2);
  const int scol = (lx & 3) * 8;
  const unsigned short* Asrc = A + (size_t)(m0 + srow) * K + scol;
  const unsigned short* Bsrc = B + (size_t)(n0 + srow) * K + scol;

  f32x4 acc[8][4];
#pragma unroll
  for (int i = 0; i < 8; i++)
#pragma unroll
    for (int j = 0; j < 4; j++) acc[i][j] = {0.f, 0.f, 0.f, 0.f};

  auto stgA = [&](int buf, int t, int h) {
    const size_t off = (size_t)t * 64 + (size_t)(h * 128) * K;
    gload16(Asrc + off,      &As[buf][h * 4096 + w * 512]);
    gload16(Asrc + off + 32, &As[buf][8192 + h * 4096 + w * 512]);
  };
  auto stgB = [&](int buf, int t, int h) {
    const size_t off = (size_t)t * 64 + (size_t)(h * 128) * K;
    gload16(Bsrc + off,      &Bs[buf][h * 4096 + w * 512]);
    gload16(Bsrc + off + 32, &Bs[buf][8192 + h * 4096 + w * 512]);
  };
  auto rdA = [&](int buf, int mi, int ks) -> bf16x8 {
    return *(const bf16x8*)&As[buf][ks * 8192 + (wm * 128 + mi * 16 + ln) * 32 + kswz];
  };
  auto rdB = [&](int buf, int nj, int ks) -> bf16x8 {
    return *(const bf16x8*)&Bs[buf][ks * 8192 + (wn * 64 + nj * 16 + ln) * 32 + kswz];
  };

  const int NT = K >> 6;

  stgA(0, 0, 0); stgA(0, 0, 1); stgB(0, 0, 0); stgB(0, 0, 1);
  stgA(1, 1, 0); stgA(1, 1, 1);
  asm volatile("s_waitcnt vmcnt(4)" ::: "memory");
  __builtin_amdgcn_s_barrier();

  bf16x8 a0[4][2], a1[4][2], b01[2][2], b23[2][2];

#pragma unroll 2
  for (int t = 0; t < NT; t++) {
    const int cur = t & 1, nxt = cur ^ 1;

    // ---- phase 0: read a0 + b01 (12); stage B0(t+1); Qa = a0 x b01 ----
#pragma unroll
    for (int i = 0; i < 4; i++) { a0[i][0] = rdA(cur, i, 0); a0[i][1] = rdA(cur, i, 1); }
#pragma unroll
    for (int j = 0; j < 2; j++) { b01[j][0] = rdB(cur, j, 0); b01[j][1] = rdB(cur, j, 1); }
    if (t + 1 < NT) stgB(nxt, t + 1, 0);
    asm volatile("s_waitcnt lgkmcnt(8)" ::: "memory");
    __builtin_amdgcn_s_barrier();
    asm volatile("s_waitcnt lgkmcnt(0)" ::: "memory");
    __builtin_amdgcn_sched_barrier(0);
    __builtin_amdgcn_s_setprio(1);
#pragma unroll
    for (int i = 0; i < 4; i++)
#pragma unroll
      for (int j = 0; j < 2; j++) {
        acc[i][j] = __builtin_amdgcn_mfma_f32_16x16x32_bf16(a0[i][0], b01[j][0], acc[i][j], 0, 0, 0);
        acc[i][j] = __builtin_amdgcn_mfma_f32_16x16x32_bf16(a0[i][1], b01[j][1], acc[i][j], 0, 0, 0);
      }
    __builtin_amdgcn_s_setprio(0);
    __builtin_amdgcn_s_barrier();

    // ---- phase 1: read b23 (4); stage B1(t+1); Qd = a0 x b23 ----
#pragma unroll
    for (int j = 0; j < 2; j++) { b23[j][0] = rdB(cur, 2 + j, 0); b23[j][1] = rdB(cur, 2 + j, 1); }
    if (t + 1 < NT) stgB(nxt, t + 1, 1);
    __builtin_amdgcn_s_barrier();
    asm volatile("s_waitcnt lgkmcnt(0)" ::: "memory");
    __builtin_amdgcn_sched_barrier(0);
    __builtin_amdgcn_s_setprio(1);
#pragma unroll
    for (int i = 0; i < 4; i++)
#pragma unroll
      for (int j = 0; j < 2; j++) {
        acc[i][2 + j] = __builtin_amdgcn_mfma_f32_16x16x32_bf16(a0[i][0], b23[j][0], acc[i][2 + j], 0, 0, 0);
        acc[i][2 + j] = __builtin_amdgcn_mfma_f32_16x16x32_bf16(a0[i][1], b23[j][1], acc[i][2 + j], 0, 0, 0);
      }
    __builtin_amdgcn_s_setprio(0);
    __builtin_amdgcn_s_barrier();

    // ---- phase 2: read a1 (8); no stage; Qc = a1 x b23 ----
#pragma unroll
    for (int i = 0; i < 4; i++) { a1[i][0] = rdA(cur, 4 + i, 0); a1[i][1] = rdA(cur, 4 + i, 1); }
    asm volatile("s_waitcnt lgkmcnt(4)" ::: "memory");
    __builtin_amdgcn_s_barrier();
    asm volatile("s_waitcnt lgkmcnt(0)" ::: "memory");
    __builtin_amdgcn_sched_barrier(0);
    __builtin_amdgcn_s_setprio(1);
#pragma unroll
    for (int i = 0; i < 4; i++)
#pragma unroll
      for (int j = 0; j < 2; j++) {
        acc[4 + i][2 + j] = __builtin_amdgcn_mfma_f32_16x16x32_bf16(a1[i][0], b23[j][0], acc[4 + i][2 + j], 0, 0, 0);
        acc[4 + i][2 + j] = __builtin_amdgcn_mfma_f32_16x16x32_bf16(a1[i][1], b23[j][1], acc[4 + i][2 + j], 0, 0, 0);
      }
    __builtin_amdgcn_s_setprio(0);
    __builtin_amdgcn_s_barrier();

    // ---- phase 3: stage A0+A1(t+2) into cur; Qb = a1 x b01; boundary ----
    if (t + 2 < NT) { stgA(cur, t + 2, 0); stgA(cur, t + 2, 1); }
    __builtin_amdgcn_s_barrier();
    __builtin_amdgcn_sched_barrier(0);
    __builtin_amdgcn_s_setprio(1);
#pragma unroll
    for (int i = 0; i < 4; i++)
#pragma unroll
      for (int j = 0; j < 2; j++) {
        acc[4 + i][j] = __builtin_amdgcn_mfma_f32_16x16x32_bf16(a1[i][0], b01[j][0], acc[4 + i][j], 0, 0, 0);
        acc[4 + i][j] = __builtin_amdgcn_mfma_f32_16x16x32_bf16(a1[i][1], b01[j][1], acc[4 + i][j], 0, 0, 0);
      }
    __builtin_amdgcn_s_setprio(0);
    if (t + 2 < NT) asm volatile("s_waitcnt vmcnt(4)" ::: "memory");
    else            asm volatile("s_waitcnt vmcnt(0)" ::: "memory");
    __builtin_amdgcn_s_barrier();
  }

  // Epilogue. C/D layout (m89): col = ln, row = kq*4 + r.
#pragma unroll
  for (int mi = 0; mi < 8; mi++) {
    const int row_base = m0 + wm * 128 + mi * 16 + kq * 4;
#pragma unroll
    for (int nj = 0; nj < 4; nj++) {
      const int col = n0 + wn * 64 + nj * 16 + ln;
#pragma unroll
      for (int r = 0; r < 4; r++) {
        const size_t idx = (size_t)(row_base + r) * N + col;
        if (COF32) ((float*)Cv)[idx] = acc[mi][nj][r];
        else       ((unsigned short*)Cv)[idx] = f2bf(acc[mi][nj][r]);
      }
    }
  }
}

// ---------------------------------------------------------------------------
// Transposed flash attention (R13 structure + T5 setprio) with XCD-affinity
// block remap: XCD (j&7) owns 4 (b,h) groups x 16 qb; within a group qb
// alternates heavy/light. The 16 blocks sharing one (b,h)'s K/V (2MB)
// co-locate on one XCD -> K/V prefetch hits L2.
// ---------------------------------------------------------------------------
#define TSEQ 2048
#define CDIM 2048
#define QKVLD 6144
#define DH 128
#define NEG_BIG (-1.0e30f)
#define K_LD 136
#define VT_LD 76
#define P_LD 72

__global__ __launch_bounds__(512, 4) void attn(
    const unsigned short* __restrict__ qkv,
    unsigned short* __restrict__ y) {
  __shared__ __align__(16) unsigned short Klds[64 * K_LD];
  __shared__ __align__(16) unsigned short Vt[DH * VT_LD];
  __shared__ __align__(16) unsigned short Plds[8 * 16 * P_LD];

  const int tid  = threadIdx.x;
  const int lane = tid & 63;
  const int w    = tid >> 6;          // 0..7
  const int ln   = lane & 15;
  const int kq   = lane >> 4;

  // XCD-affinity decode (512 blocks = 8 XCD x 4 (b,h) x 16 qb)
  const int j    = blockIdx.x;
  const int xcd  = j & 7;
  const int k    = j >> 3;            // 0..63
  const int bh   = xcd * 4 + (k >> 4);// 0..31
  const int b    = bh >> 4;
  const int h    = bh & 15;
  const int qbi  = k & 15;
  const int qb   = (qbi & 1) ? (15 - (qbi >> 1)) : (qbi >> 1);  // alternate heavy/light
  const int q0   = qb * 128;
  const int qrow = q0 + w * 16 + ln;

  const size_t baseQ = (size_t)b * TSEQ * QKVLD + (size_t)h * DH;
  const size_t baseK = baseQ + CDIM;
  const size_t baseV = baseQ + 2 * CDIM;

  bf16x8 qf[4];
  {
    const float scale = 0.08838834764831845f;
    const unsigned short* qp = qkv + baseQ + (size_t)qrow * QKVLD + kq * 8;
#pragma unroll
    for (int kc = 0; kc < 4; kc++) {
      u16x8 raw = *(const u16x8*)(qp + kc * 32);
      u16x8 t;
#pragma unroll
      for (int jj = 0; jj < 8; jj++) t[jj] = f2bf(bf2f(raw[jj]) * scale);
      qf[kc] = __builtin_bit_cast(bf16x8, t);
    }
  }

  const int kRow = tid >> 4;
  const int kCol = (tid & 15) * 8;
  const int vK4  = (tid & 15) * 4;
  const int vD0  = (tid >> 4) * 4;
  const unsigned short* Kg = qkv + baseK + (size_t)kRow * QKVLD + kCol;
  const unsigned short* Vg = qkv + baseV + (size_t)vK4 * QKVLD + vD0;

  u16x8 kreg[2];
  u16x4 vreg[4];
#pragma unroll
  for (int it = 0; it < 2; it++)
    kreg[it] = *(const u16x8*)(Kg + (size_t)(it * 32) * QKVLD);
#pragma unroll
  for (int r = 0; r < 4; r++)
    vreg[r] = *(const u16x4*)(Vg + (size_t)r * QKVLD);

  f32x4 o[8];
#pragma unroll
  for (int i = 0; i < 8; i++) o[i] = {0.f, 0.f, 0.f, 0.f};
  float m = NEG_BIG, l = 0.f;
  unsigned short* pw = &Plds[w * 16 * P_LD];

  const int ktEnd   = 2 * qb + 2;
  const int myKtMax = (q0 + w * 16) >> 6;

  for (int kt = 0; kt < ktEnd; kt++) {
    __syncthreads();

#pragma unroll
    for (int it = 0; it < 2; it++)
      *(u16x8*)&Klds[(kRow + it * 32) * K_LD + kCol] = kreg[it];
#pragma unroll
    for (int jj = 0; jj < 4; jj++) {
      u16x4 t = {vreg[0][jj], vreg[1][jj], vreg[2][jj], vreg[3][jj]};
      *(u16x4*)&Vt[(vD0 + jj) * VT_LD + vK4] = t;
    }
    __syncthreads();

    if (kt + 1 < ktEnd) {
      const size_t off = (size_t)(kt + 1) * 64 * QKVLD;
#pragma unroll
      for (int it = 0; it < 2; it++)
        kreg[it] = *(const u16x8*)(Kg + off + (size_t)(it * 32) * QKVLD);
#pragma unroll
      for (int r = 0; r < 4; r++)
        vreg[r] = *(const u16x4*)(Vg + off + (size_t)r * QKVLD);
    }

    if (kt > myKtMax) continue;

    f32x4 s[4];
    __builtin_amdgcn_s_setprio(1);
#pragma unroll
    for (int nt = 0; nt < 4; nt++) {
      s[nt] = {0.f, 0.f, 0.f, 0.f};
#pragma unroll
      for (int kc = 0; kc < 4; kc++) {
        bf16x8 kb = *(const bf16x8*)&Klds[(nt * 16 + ln) * K_LD + kc * 32 + kq * 8];
        s[nt] = __builtin_amdgcn_mfma_f32_16x16x32_bf16(kb, qf[kc], s[nt], 0, 0, 0);
      }
    }
    __builtin_amdgcn_s_setprio(0);

    if (kt == myKtMax) {
      const int kbase = kt * 64 + kq * 4;
#pragma unroll
      for (int nt = 0; nt < 4; nt++)
#pragma unroll
        for (int r = 0; r < 4; r++)
          if (kbase + nt * 16 + r > qrow) s[nt][r] = NEG_BIG;
    }

    float mt;
    {
      f32x4 t01 = {fmaxf(s[0][0], s[0][1]), fmaxf(s[0][2], s[0][3]),
                   fmaxf(s[1][0], s[1][1]), fmaxf(s[1][2], s[1][3])};
      f32x4 t23 = {fmaxf(s[2][0], s[2][1]), fmaxf(s[2][2], s[2][3]),
                   fmaxf(s[3][0], s[3][1]), fmaxf(s[3][2], s[3][3])};
      f32x4 t = {fmaxf(t01[0], t01[1]), fmaxf(t01[2], t01[3]),
                 fmaxf(t23[0], t23[1]), fmaxf(t23[2], t23[3])};
      mt = fmaxf(fmaxf(t[0], t[1]), fmaxf(t[2], t[3]));
    }
    mt = fmaxf(mt, __shfl_xor(mt, 16, 64));
    mt = fmaxf(mt, __shfl_xor(mt, 32, 64));

    const bool defer = __all(mt - m <= 8.0f);
    const float mn = defer ? m : fmaxf(m, mt);
    const float alpha = defer ? 1.0f : __expf(m - mn);
    m = mn;

    float ps = 0.f;
#pragma unroll
    for (int nt = 0; nt < 4; nt++) {
      u16x4 pbits;
#pragma unroll
      for (int r = 0; r < 4; r++) {
        const float p = __expf(s[nt][r] - mn);
        ps += p;
        pbits[r] = f2bf(p);
      }
      *(u16x4*)&pw[ln * P_LD + nt * 16 + kq * 4] = pbits;
    }
    ps += __shfl_xor(ps, 16, 64);
    ps += __shfl_xor(ps, 32, 64);
    l = l * alpha + ps;

    if (!defer) {
#pragma unroll
      for (int i = 0; i < 8; i++)
#pragma unroll
        for (int r = 0; r < 4; r++) o[i][r] *= alpha;
    }

    bf16x8 pa[2];
#pragma unroll
    for (int kc = 0; kc < 2; kc++)
      pa[kc] = *(const bf16x8*)&pw[ln * P_LD + kc * 32 + kq * 8];
    __builtin_amdgcn_s_setprio(1);
#pragma unroll
    for (int nt = 0; nt < 8; nt++)
#pragma unroll
      for (int kc = 0; kc < 2; kc++) {
        bf16x8 vb = *(const bf16x8*)&Vt[(nt * 16 + ln) * VT_LD + kc * 32 + kq * 8];
        o[nt] = __builtin_amdgcn_mfma_f32_16x16x32_bf16(vb, pa[kc], o[nt], 0, 0, 0);
      }
    __builtin_amdgcn_s_setprio(0);
  }

  const float inv = 1.f / l;
  unsigned short* yp = y + (size_t)(b * TSEQ + qrow) * CDIM + (size_t)h * DH + kq * 4;
#pragma unroll
  for (int nt = 0; nt < 8; nt++) {
    u16x4 ov;
#pragma unroll
    for (int r = 0; r < 4; r++) ov[r] = f2bf(o[nt][r] * inv);
    *(u16x4*)(yp + nt * 16) = ov;
  }
}

extern "C" void kernel_launch(void* const* d_in, const int* in_sizes, int n_in,
                              void* d_out, int out_size, void* d_ws, size_t ws_size,
                              hipStream_t stream) {
  const float* x     = (const float*)d_in[0];  // fp32 [4096][2048]
  const float* Wqkv  = (const float*)d_in[1];  // fp32 [6144][2048]
  const float* Wproj = (const float*)d_in[2];  // fp32 [2048][2048]
  void* out = d_out;                                   // fp32 [4096][2048]

  unsigned short* qkv = (unsigned short*)d_ws;         // bf16, 48MB
  unsigned short* y   = qkv + (size_t)4096 * 6144;     // bf16, 16MB (aliases x_bf)
  unsigned short* xbf = y;                             // x_bf dead before attn writes y
  unsigned short* wbf = y + (size_t)4096 * 2048;       // 24MB (Wqkv_bf)

  const size_t need3 = (size_t)(48 + 16 + 24 + 8) * 1024 * 1024;  // 96MB
  if (ws_size >= need3) {
    // Wproj_bf in its own region: fuse ALL converts into one pre-GEMM launch.
    unsigned short* wpbf = wbf + (size_t)6144 * 2048;  // 8MB
    f32_to_bf16_3<<<dim3(2048), 256, 0, stream>>>(
        x, xbf, (4096 * 2048) / 8,
        Wqkv, wbf, (6144 * 2048) / 8,
        Wproj, wpbf, (2048 * 2048) / 8);
    gemm8<false><<<dim3(24, 16), 512, 0, stream>>>(xbf, wbf, qkv, 4096, 6144, 2048);
    attn<<<dim3(512), 512, 0, stream>>>(qkv, y);
    gemm_bf<true, true><<<dim3(16, 32), 256, 0, stream>>>(y, wpbf, out, 4096, 2048, 2048);
  } else {
    f32_to_bf16_2<<<dim3(2048), 256, 0, stream>>>(x, xbf, (4096 * 2048) / 8,
                                                  Wqkv, wbf, (6144 * 2048) / 8);
    gemm8<false><<<dim3(24, 16), 512, 0, stream>>>(xbf, wbf, qkv, 4096, 6144, 2048);
    f32_to_bf16<<<dim3(2048), 256, 0, stream>>>(Wproj, wbf, (2048 * 2048) / 8);  // Wqkv_bf dead
    attn<<<dim3(512), 512, 0, stream>>>(qkv, y);
    gemm_bf<true, true><<<dim3(16, 32), 256, 0, stream>>>(y, wbf, out, 4096, 2048, 2048);
  }
}

// Round 10
// 378.736 us; speedup vs baseline: 1.0775x; 1.0775x over previous
//
#include <hip/hip_runtime.h>
#include <hip/hip_bf16.h>
#include <stdint.h>

// R18: R16 base (best verified, 384.5us; R17's 3-change bundle reverted) with
// ONE change: both GEMMs retiled to BM=128 x BN=256 x BK=64 ("gemm_hp").
//  - LDS 96KB (A dbuf 32K + B dbuf 64K) -> QKV grid 768 = 3 EXACT rounds,
//    proj grid 256 = 1 EXACT round (gemm8's 384@1block/CU was 1.5 rounds,
//    25% machine idle).
//  - 2 phases/tile x 16 MFMA (same 8 MFMA/barrier as 256^2 template).
//    p0: read a(8)+b01(4), stage Bh0(t+1); p1: read b23(4), stage Bh1(t+1)
//    + A(t+2) (A[cur] free after p0). Boundary vmcnt(2).
//  - Addressing reuses R12's verified maps (lane-perm lx=ln^2 for ln>=32,
//    srow=w*16+(lx>>2), kswz=(kq*8)^((ln&8)<<1)); only dest bases change.
// attn/converts identical to R16.

typedef __bf16 bf16x8 __attribute__((ext_vector_type(8)));
typedef float f32x4 __attribute__((ext_vector_type(4)));
typedef unsigned short u16x8 __attribute__((ext_vector_type(8)));
typedef unsigned short u16x4 __attribute__((ext_vector_type(4)));

__device__ __forceinline__ unsigned short f2bf(float f) {
  unsigned int u = __builtin_bit_cast(unsigned int, f);
  u += 0x7fff + ((u >> 16) & 1);   // RNE; values are finite
  return (unsigned short)(u >> 16);
}
__device__ __forceinline__ float bf2f(unsigned short u) {
  return __builtin_bit_cast(float, (unsigned int)u << 16);
}

__device__ __forceinline__ u16x8 cvt8(const float* p) {
  f32x4 lo = *(const f32x4*)p;
  f32x4 hi = *(const f32x4*)(p + 4);
  u16x8 r;
#pragma unroll
  for (int j = 0; j < 4; j++) { r[j] = f2bf(lo[j]); r[4 + j] = f2bf(hi[j]); }
  return r;
}

// async 16B global->LDS copy. LDS dest is wave-uniform base; HW adds lane*16.
__device__ __forceinline__ void gload16(const void* g, void* l) {
  __builtin_amdgcn_global_load_lds(
      (const __attribute__((address_space(1))) void*)g,
      (__attribute__((address_space(3))) void*)l, 16, 0, 0);
}

// ---------------------------------------------------------------------------
// fp32 -> bf16 bulk converts. Memory-bound.
// ---------------------------------------------------------------------------
__global__ __launch_bounds__(256) void f32_to_bf16(
    const float* __restrict__ src, unsigned short* __restrict__ dst, int n8) {
  int i = blockIdx.x * 256 + threadIdx.x;
  const int stride = gridDim.x * 256;
  for (; i < n8; i += stride) {
    u16x8 v = cvt8(src + (size_t)i * 8);
    *(u16x8*)&dst[(size_t)i * 8] = v;
  }
}

// two-array fused variant (x and Wqkv in one launch)
__global__ __launch_bounds__(256) void f32_to_bf16_2(
    const float* __restrict__ s0, unsigned short* __restrict__ d0, int n80,
    const float* __restrict__ s1, unsigned short* __restrict__ d1, int n81) {
  int i = blockIdx.x * 256 + threadIdx.x;
  const int stride = gridDim.x * 256;
  const int tot = n80 + n81;
  for (; i < tot; i += stride) {
    if (i < n80) {
      u16x8 v = cvt8(s0 + (size_t)i * 8);
      *(u16x8*)&d0[(size_t)i * 8] = v;
    } else {
      const int j = i - n80;
      u16x8 v = cvt8(s1 + (size_t)j * 8);
      *(u16x8*)&d1[(size_t)j * 8] = v;
    }
  }
}

// ---------------------------------------------------------------------------
// gemm_hp: C[M][N] = A[M][K] @ B[N][K]^T, bf16 in, C bf16 or fp32.
// BM=128, BN=256, BK=64, 512 threads (8 waves as 2M x 4N, each 64x64 out).
// LDS: As[2][2ks][128][32] 32KB + Bs[2][2ks][256][32] 64KB = 96KB.
// Swizzle: elem col ^= 16 iff row&8 (st_16x32); stage source pre-permuted
// (lx = lane^2 for lane>=32), reads use kswz = (kq*8)^((ln&8)<<1).
// Schedule/tile (NT=K/64): p0{rd a*8+b01*4; stage Bh0(t+1); bar; lgkm0;
// 16 MFMA}; p1{rd b23*4; stage Bh1(t+1)+A(t+2); bar; lgkm0; 16 MFMA;
// vmcnt(2); bar}. XCD-bijective tile remap (nwg%8==0).
// ---------------------------------------------------------------------------
template <bool COF32>
__global__ __launch_bounds__(512, 2) void gemm_hp(
    const unsigned short* __restrict__ A, const unsigned short* __restrict__ B,
    void* __restrict__ Cv, int M, int N, int K) {
  __shared__ __align__(1024) unsigned short As[2][8192];   // [buf][ks*4096+row*32+c]
  __shared__ __align__(1024) unsigned short Bs[2][16384];  // [buf][ks*8192+row*32+c]

  const int tid  = threadIdx.x;
  const int lane = tid & 63;
  const int w    = tid >> 6;         // 0..7
  const int ln   = lane & 15;
  const int kq   = lane >> 4;
  const int wm   = w >> 2;           // 0..1 (64-row half)
  const int wn   = w & 3;            // 0..3 (64-col quarter)

  const int nx  = gridDim.x;
  const int nwg = gridDim.x * gridDim.y;
  const int lin = blockIdx.y * nx + blockIdx.x;
  const int swz = (lin & 7) * (nwg >> 3) + (lin >> 3);
  const int m0 = (swz / nx) * 128;
  const int n0 = (swz % nx) * 256;

  const int kswz = (kq * 8) ^ ((ln & 8) << 1);

  const int lx = lane ^ (((lane >> 5) & 1) << 1);
  const int srow = w * 16 + (lx >> 2);
  const int scol = (lx & 3) * 8;
  const unsigned short* Asrc = A + (size_t)(m0 + srow) * K + scol;
  const unsigned short* Bsrc0 = B + (size_t)(n0 + srow) * K + scol;
  const unsigned short* Bsrc1 = B + (size_t)(n0 + 128 + srow) * K + scol;

  f32x4 acc[4][4];
#pragma unroll
  for (int i = 0; i < 4; i++)
#pragma unroll
    for (int j = 0; j < 4; j++) acc[i][j] = {0.f, 0.f, 0.f, 0.f};

  // A tile: 2 gloads (ks halves), 128 rows each covered by 8 waves x 16 rows
  auto stgA = [&](int buf, int t) {
    const size_t tc = (size_t)t * 64;
    gload16(Asrc + tc,      &As[buf][w * 512]);          // ks=0
    gload16(Asrc + tc + 32, &As[buf][4096 + w * 512]);   // ks=1
  };
  // B tile half h (ks half): 2 gloads (row halves j)
  auto stgBh = [&](int buf, int t, int h) {
    const size_t tc = (size_t)t * 64 + h * 32;
    gload16(Bsrc0 + tc, &Bs[buf][h * 8192 + w * 512]);          // rows 0..127
    gload16(Bsrc1 + tc, &Bs[buf][h * 8192 + 4096 + w * 512]);   // rows 128..255
  };
  auto rdA = [&](int buf, int mi, int ks) -> bf16x8 {
    return *(const bf16x8*)&As[buf][ks * 4096 + (wm * 64 + mi * 16 + ln) * 32 + kswz];
  };
  auto rdB = [&](int buf, int nj, int ks) -> bf16x8 {
    return *(const bf16x8*)&Bs[buf][ks * 8192 + (wn * 64 + nj * 16 + ln) * 32 + kswz];
  };

  const int NT = K >> 6;   // 32 (K=2048)

  // prologue: T0 fully (A:2 + B:4), then A(1) (2). Newest 2 may fly.
  stgA(0, 0); stgBh(0, 0, 0); stgBh(0, 0, 1);
  stgA(1, 1);
  asm volatile("s_waitcnt vmcnt(2)" ::: "memory");
  __builtin_amdgcn_s_barrier();

  bf16x8 a[4][2], b01[2][2], b23[2][2];

#pragma unroll 2
  for (int t = 0; t < NT; t++) {
    const int cur = t & 1, nxt = cur ^ 1;

    // ---- phase 0: read a (8) + b01 (4); stage Bh0(t+1); Q01 = a x b01 ----
#pragma unroll
    for (int i = 0; i < 4; i++) { a[i][0] = rdA(cur, i, 0); a[i][1] = rdA(cur, i, 1); }
#pragma unroll
    for (int j = 0; j < 2; j++) { b01[j][0] = rdB(cur, j, 0); b01[j][1] = rdB(cur, j, 1); }
    if (t + 1 < NT) stgBh(nxt, t + 1, 0);
    asm volatile("s_waitcnt lgkmcnt(8)" ::: "memory");   // pre-drain 4 of 12
    __builtin_amdgcn_s_barrier();
    asm volatile("s_waitcnt lgkmcnt(0)" ::: "memory");
    __builtin_amdgcn_sched_barrier(0);
    __builtin_amdgcn_s_setprio(1);
#pragma unroll
    for (int i = 0; i < 4; i++)
#pragma unroll
      for (int j = 0; j < 2; j++) {
        acc[i][j] = __builtin_amdgcn_mfma_f32_16x16x32_bf16(a[i][0], b01[j][0], acc[i][j], 0, 0, 0);
        acc[i][j] = __builtin_amdgcn_mfma_f32_16x16x32_bf16(a[i][1], b01[j][1], acc[i][j], 0, 0, 0);
      }
    __builtin_amdgcn_s_setprio(0);
    __builtin_amdgcn_s_barrier();

    // ---- phase 1: read b23 (4); stage Bh1(t+1) + A(t+2) [A cur free];
    //      Q23 = a x b23; boundary vmcnt ----
#pragma unroll
    for (int j = 0; j < 2; j++) { b23[j][0] = rdB(cur, 2 + j, 0); b23[j][1] = rdB(cur, 2 + j, 1); }
    if (t + 1 < NT) stgBh(nxt, t + 1, 1);
    if (t + 2 < NT) stgA(cur, t + 2);
    __builtin_amdgcn_s_barrier();
    asm volatile("s_waitcnt lgkmcnt(0)" ::: "memory");
    __builtin_amdgcn_sched_barrier(0);
    __builtin_amdgcn_s_setprio(1);
#pragma unroll
    for (int i = 0; i < 4; i++)
#pragma unroll
      for (int j = 0; j < 2; j++) {
        acc[i][2 + j] = __builtin_amdgcn_mfma_f32_16x16x32_bf16(a[i][0], b23[j][0], acc[i][2 + j], 0, 0, 0);
        acc[i][2 + j] = __builtin_amdgcn_mfma_f32_16x16x32_bf16(a[i][1], b23[j][1], acc[i][2 + j], 0, 0, 0);
      }
    __builtin_amdgcn_s_setprio(0);
    if (t + 2 < NT) asm volatile("s_waitcnt vmcnt(2)" ::: "memory");
    else            asm volatile("s_waitcnt vmcnt(0)" ::: "memory");
    __builtin_amdgcn_s_barrier();
  }

  // Epilogue. C/D layout (m89): col = ln, row = kq*4 + r.
#pragma unroll
  for (int mi = 0; mi < 4; mi++) {
    const int row_base = m0 + wm * 64 + mi * 16 + kq * 4;
#pragma unroll
    for (int nj = 0; nj < 4; nj++) {
      const int col = n0 + wn * 64 + nj * 16 + ln;
#pragma unroll
      for (int r = 0; r < 4; r++) {
        const size_t idx = (size_t)(row_base + r) * N + col;
        if (COF32) ((float*)Cv)[idx] = acc[mi][nj][r];
        else       ((unsigned short*)Cv)[idx] = f2bf(acc[mi][nj][r]);
      }
    }
  }
}

// ---------------------------------------------------------------------------
// Transposed flash attention (R16 verbatim: R13 structure + T5 setprio).
// ---------------------------------------------------------------------------
#define TSEQ 2048
#define CDIM 2048
#define QKVLD 6144
#define DH 128
#define NEG_BIG (-1.0e30f)
#define K_LD 136
#define VT_LD 76
#define P_LD 72

__global__ __launch_bounds__(512, 4) void attn(
    const unsigned short* __restrict__ qkv,
    unsigned short* __restrict__ y) {
  __shared__ __align__(16) unsigned short Klds[64 * K_LD];
  __shared__ __align__(16) unsigned short Vt[DH * VT_LD];
  __shared__ __align__(16) unsigned short Plds[8 * 16 * P_LD];

  const int tid  = threadIdx.x;
  const int lane = tid & 63;
  const int w    = tid >> 6;          // 0..7
  const int ln   = lane & 15;
  const int kq   = lane >> 4;

  const int idx  = blockIdx.x;
  const int half = idx >> 8;
  const int qbi  = idx & 15;
  const int qb   = half ? qbi : 15 - qbi;
  const int h    = (idx >> 4) & 15;
  const int b    = half;
  const int q0   = qb * 128;
  const int qrow = q0 + w * 16 + ln;

  const size_t baseQ = (size_t)b * TSEQ * QKVLD + (size_t)h * DH;
  const size_t baseK = baseQ + CDIM;
  const size_t baseV = baseQ + 2 * CDIM;

  bf16x8 qf[4];
  {
    const float scale = 0.08838834764831845f;
    const unsigned short* qp = qkv + baseQ + (size_t)qrow * QKVLD + kq * 8;
#pragma unroll
    for (int kc = 0; kc < 4; kc++) {
      u16x8 raw = *(const u16x8*)(qp + kc * 32);
      u16x8 t;
#pragma unroll
      for (int j = 0; j < 8; j++) t[j] = f2bf(bf2f(raw[j]) * scale);
      qf[kc] = __builtin_bit_cast(bf16x8, t);
    }
  }

  const int kRow = tid >> 4;
  const int kCol = (tid & 15) * 8;
  const int vK4  = (tid & 15) * 4;
  const int vD0  = (tid >> 4) * 4;
  const unsigned short* Kg = qkv + baseK + (size_t)kRow * QKVLD + kCol;
  const unsigned short* Vg = qkv + baseV + (size_t)vK4 * QKVLD + vD0;

  u16x8 kreg[2];
  u16x4 vreg[4];
#pragma unroll
  for (int it = 0; it < 2; it++)
    kreg[it] = *(const u16x8*)(Kg + (size_t)(it * 32) * QKVLD);
#pragma unroll
  for (int r = 0; r < 4; r++)
    vreg[r] = *(const u16x4*)(Vg + (size_t)r * QKVLD);

  f32x4 o[8];
#pragma unroll
  for (int i = 0; i < 8; i++) o[i] = {0.f, 0.f, 0.f, 0.f};
  float m = NEG_BIG, l = 0.f;
  unsigned short* pw = &Plds[w * 16 * P_LD];

  const int ktEnd   = 2 * qb + 2;
  const int myKtMax = (q0 + w * 16) >> 6;

  for (int kt = 0; kt < ktEnd; kt++) {
    __syncthreads();

#pragma unroll
    for (int it = 0; it < 2; it++)
      *(u16x8*)&Klds[(kRow + it * 32) * K_LD + kCol] = kreg[it];
#pragma unroll
    for (int j = 0; j < 4; j++) {
      u16x4 t = {vreg[0][j], vreg[1][j], vreg[2][j], vreg[3][j]};
      *(u16x4*)&Vt[(vD0 + j) * VT_LD + vK4] = t;
    }
    __syncthreads();

    if (kt + 1 < ktEnd) {
      const size_t off = (size_t)(kt + 1) * 64 * QKVLD;
#pragma unroll
      for (int it = 0; it < 2; it++)
        kreg[it] = *(const u16x8*)(Kg + off + (size_t)(it * 32) * QKVLD);
#pragma unroll
      for (int r = 0; r < 4; r++)
        vreg[r] = *(const u16x4*)(Vg + off + (size_t)r * QKVLD);
    }

    if (kt > myKtMax) continue;

    f32x4 s[4];
    __builtin_amdgcn_s_setprio(1);
#pragma unroll
    for (int nt = 0; nt < 4; nt++) {
      s[nt] = {0.f, 0.f, 0.f, 0.f};
#pragma unroll
      for (int kc = 0; kc < 4; kc++) {
        bf16x8 kb = *(const bf16x8*)&Klds[(nt * 16 + ln) * K_LD + kc * 32 + kq * 8];
        s[nt] = __builtin_amdgcn_mfma_f32_16x16x32_bf16(kb, qf[kc], s[nt], 0, 0, 0);
      }
    }
    __builtin_amdgcn_s_setprio(0);

    if (kt == myKtMax) {
      const int kbase = kt * 64 + kq * 4;
#pragma unroll
      for (int nt = 0; nt < 4; nt++)
#pragma unroll
        for (int r = 0; r < 4; r++)
          if (kbase + nt * 16 + r > qrow) s[nt][r] = NEG_BIG;
    }

    float mt;
    {
      f32x4 t01 = {fmaxf(s[0][0], s[0][1]), fmaxf(s[0][2], s[0][3]),
                   fmaxf(s[1][0], s[1][1]), fmaxf(s[1][2], s[1][3])};
      f32x4 t23 = {fmaxf(s[2][0], s[2][1]), fmaxf(s[2][2], s[2][3]),
                   fmaxf(s[3][0], s[3][1]), fmaxf(s[3][2], s[3][3])};
      f32x4 t = {fmaxf(t01[0], t01[1]), fmaxf(t01[2], t01[3]),
                 fmaxf(t23[0], t23[1]), fmaxf(t23[2], t23[3])};
      mt = fmaxf(fmaxf(t[0], t[1]), fmaxf(t[2], t[3]));
    }
    mt = fmaxf(mt, __shfl_xor(mt, 16, 64));
    mt = fmaxf(mt, __shfl_xor(mt, 32, 64));

    const bool defer = __all(mt - m <= 8.0f);
    const float mn = defer ? m : fmaxf(m, mt);
    const float alpha = defer ? 1.0f : __expf(m - mn);
    m = mn;

    float ps = 0.f;
#pragma unroll
    for (int nt = 0; nt < 4; nt++) {
      u16x4 pbits;
#pragma unroll
      for (int r = 0; r < 4; r++) {
        const float p = __expf(s[nt][r] - mn);
        ps += p;
        pbits[r] = f2bf(p);
      }
      *(u16x4*)&pw[ln * P_LD + nt * 16 + kq * 4] = pbits;
    }
    ps += __shfl_xor(ps, 16, 64);
    ps += __shfl_xor(ps, 32, 64);
    l = l * alpha + ps;

    if (!defer) {
#pragma unroll
      for (int i = 0; i < 8; i++)
#pragma unroll
        for (int r = 0; r < 4; r++) o[i][r] *= alpha;
    }

    bf16x8 pa[2];
#pragma unroll
    for (int kc = 0; kc < 2; kc++)
      pa[kc] = *(const bf16x8*)&pw[ln * P_LD + kc * 32 + kq * 8];
    __builtin_amdgcn_s_setprio(1);
#pragma unroll
    for (int nt = 0; nt < 8; nt++)
#pragma unroll
      for (int kc = 0; kc < 2; kc++) {
        bf16x8 vb = *(const bf16x8*)&Vt[(nt * 16 + ln) * VT_LD + kc * 32 + kq * 8];
        o[nt] = __builtin_amdgcn_mfma_f32_16x16x32_bf16(vb, pa[kc], o[nt], 0, 0, 0);
      }
    __builtin_amdgcn_s_setprio(0);
  }

  const float inv = 1.f / l;
  unsigned short* yp = y + (size_t)(b * TSEQ + qrow) * CDIM + (size_t)h * DH + kq * 4;
#pragma unroll
  for (int nt = 0; nt < 8; nt++) {
    u16x4 ov;
#pragma unroll
    for (int r = 0; r < 4; r++) ov[r] = f2bf(o[nt][r] * inv);
    *(u16x4*)(yp + nt * 16) = ov;
  }
}

extern "C" void kernel_launch(void* const* d_in, const int* in_sizes, int n_in,
                              void* d_out, int out_size, void* d_ws, size_t ws_size,
                              hipStream_t stream) {
  const float* x     = (const float*)d_in[0];  // fp32 [4096][2048]
  const float* Wqkv  = (const float*)d_in[1];  // fp32 [6144][2048]
  const float* Wproj = (const float*)d_in[2];  // fp32 [2048][2048]
  void* out = d_out;                                   // fp32 [4096][2048]

  unsigned short* qkv = (unsigned short*)d_ws;         // bf16, 48MB
  unsigned short* y   = qkv + (size_t)4096 * 6144;     // bf16, 16MB (aliases x_bf)
  unsigned short* xbf = y;                             // x_bf dead before attn writes y
  unsigned short* wbf = y + (size_t)4096 * 2048;       // 24MB (Wqkv_bf, then Wproj_bf)

  f32_to_bf16_2<<<dim3(2048), 256, 0, stream>>>(x, xbf, (4096 * 2048) / 8,
                                                Wqkv, wbf, (6144 * 2048) / 8);
  gemm_hp<false><<<dim3(24, 32), 512, 0, stream>>>(xbf, wbf, qkv, 4096, 6144, 2048);
  f32_to_bf16<<<dim3(2048), 256, 0, stream>>>(Wproj, wbf, (2048 * 2048) / 8);  // Wqkv_bf dead
  attn<<<dim3(512), 512, 0, stream>>>(qkv, y);
  gemm_hp<true><<<dim3(8, 32), 512, 0, stream>>>(y, wbf, out, 4096, 2048, 2048);
}